// Round 1
// baseline (7164.262 us; speedup 1.0000x reference)
//
#include <hip/hip_runtime.h>
#include <hip/hip_bf16.h>

#define MM   16384
#define NN   65536
#define NNZV 4194304
#define BB   16

// ---------------- zuT[n*16+b] = z[b,n]*u[b,n] ----------------
__global__ void k_zuT(const float* __restrict__ z, const float* __restrict__ u,
                      float* __restrict__ zuT) {
    int n = blockIdx.x * 256 + threadIdx.x;
    float f[BB];
#pragma unroll
    for (int b = 0; b < BB; ++b)
        f[b] = z[(size_t)b * NN + n] * u[(size_t)b * NN + n];
    float4* dst = (float4*)(zuT + (size_t)n * BB);
#pragma unroll
    for (int i = 0; i < 4; ++i) dst[i] = ((float4*)f)[i];
}

// ---------------- COO scatter SpMM: outT[s,:] += v * xT[g,:] ----------------
__global__ void k_spmm_scatter(const float* __restrict__ vals,
                               const int* __restrict__ gidx,
                               const int* __restrict__ sidx,
                               const float* __restrict__ xT,
                               float* __restrict__ outT) {
    int k = blockIdx.x * 256 + threadIdx.x;
    float v = vals[k];
    size_t g = (size_t)gidx[k] * BB;
    size_t s = (size_t)sidx[k] * BB;
    const float4* src = (const float4*)(xT + g);
    float* dst = outT + s;
#pragma unroll
    for (int i = 0; i < 4; ++i) {
        float4 x = src[i];
        unsafeAtomicAdd(dst + 4 * i + 0, v * x.x);
        unsafeAtomicAdd(dst + 4 * i + 1, v * x.y);
        unsafeAtomicAdd(dst + 4 * i + 2, v * x.z);
        unsafeAtomicAdd(dst + 4 * i + 3, v * x.w);
    }
}

// ---------------- rT[m*16+b] = y[b,m] - t1T[m*16+b] ----------------
__global__ void k_rT(const float* __restrict__ y, const float* __restrict__ t1T,
                     float* __restrict__ rT) {
    int m = blockIdx.x * 256 + threadIdx.x;
    float t[BB];
#pragma unroll
    for (int i = 0; i < 4; ++i)
        ((float4*)t)[i] = ((const float4*)(t1T + (size_t)m * BB))[i];
    float f[BB];
#pragma unroll
    for (int b = 0; b < BB; ++b)
        f[b] = y[(size_t)b * MM + m] - t[b];
#pragma unroll
    for (int i = 0; i < 4; ++i)
        ((float4*)(rT + (size_t)m * BB))[i] = ((float4*)f)[i];
}

// ---------------- norm2[b] += sum_n (u[b,n]*t2T[n,b])^2 ----------------
__global__ void k_norm(const float* __restrict__ u, const float* __restrict__ t2T,
                       float* __restrict__ norm2) {
    int n = blockIdx.x * 256 + threadIdx.x;
    float t[BB];
#pragma unroll
    for (int i = 0; i < 4; ++i)
        ((float4*)t)[i] = ((const float4*)(t2T + (size_t)n * BB))[i];
    float acc[BB];
#pragma unroll
    for (int b = 0; b < BB; ++b) {
        float v = u[(size_t)b * NN + n] * t[b];
        acc[b] = v * v;
    }
#pragma unroll
    for (int b = 0; b < BB; ++b) {
#pragma unroll
        for (int off = 32; off; off >>= 1)
            acc[b] += __shfl_xor(acc[b], off, 64);
    }
    int lane = threadIdx.x & 63;
#pragma unroll
    for (int b = 0; b < BB; ++b)
        if (lane == b) unsafeAtomicAdd(norm2 + b, acc[b]);
}

// ---------------- out[b,n] = z[b,n] - eta * v / max(1,||v||) ----------------
__global__ void k_final(const float* __restrict__ z, const float* __restrict__ u,
                        const float* __restrict__ t2T, const float* __restrict__ norm2,
                        const float* __restrict__ eta, float* __restrict__ out) {
    int n = blockIdx.x * 256 + threadIdx.x;
    float t[BB];
#pragma unroll
    for (int i = 0; i < 4; ++i)
        ((float4*)t)[i] = ((const float4*)(t2T + (size_t)n * BB))[i];
    float e = eta[0];
#pragma unroll
    for (int b = 0; b < BB; ++b) {
        float denom = fmaxf(1.0f, sqrtf(norm2[b]));
        float v = u[(size_t)b * NN + n] * t[b];
        out[(size_t)b * NN + n] = z[(size_t)b * NN + n] - e * v / denom;
    }
}

extern "C" void kernel_launch(void* const* d_in, const int* in_sizes, int n_in,
                              void* d_out, int out_size, void* d_ws, size_t ws_size,
                              hipStream_t stream) {
    const float* z      = (const float*)d_in[0];
    const float* u      = (const float*)d_in[1];
    const float* y      = (const float*)d_in[2];
    const float* A_vals = (const float*)d_in[3];
    const int*   A_rows = (const int*)d_in[4];
    const int*   A_cols = (const int*)d_in[5];
    const float* eta    = (const float*)d_in[6];
    float* out = (float*)d_out;

    char* ws = (char*)d_ws;
    float* zuT   = (float*)(ws);                       // 4 MB  [N][B]
    float* t2T   = (float*)(ws + (4u << 20));          // 4 MB  [N][B]
    float* t1T   = (float*)(ws + (8u << 20));          // 1 MB  [M][B]
    float* rT    = (float*)(ws + (9u << 20));          // 1 MB  [M][B]
    float* norm2 = (float*)(ws + (10u << 20));         // 64 B  [B]

    hipMemsetAsync(t1T, 0, (size_t)MM * BB * sizeof(float), stream);
    hipMemsetAsync(t2T, 0, (size_t)NN * BB * sizeof(float), stream);
    hipMemsetAsync(norm2, 0, BB * sizeof(float), stream);

    k_zuT<<<NN / 256, 256, 0, stream>>>(z, u, zuT);
    k_spmm_scatter<<<NNZV / 256, 256, 0, stream>>>(A_vals, A_cols, A_rows, zuT, t1T);
    k_rT<<<MM / 256, 256, 0, stream>>>(y, t1T, rT);
    k_spmm_scatter<<<NNZV / 256, 256, 0, stream>>>(A_vals, A_rows, A_cols, rT, t2T);
    k_norm<<<NN / 256, 256, 0, stream>>>(u, t2T, norm2);
    k_final<<<NN / 256, 256, 0, stream>>>(z, u, t2T, norm2, eta, out);
}

// Round 4
// 1243.923 us; speedup vs baseline: 5.7594x; 5.7594x over previous
//
#include <hip/hip_runtime.h>
#include <hip/hip_bf16.h>

#define MM   16384
#define NN   65536
#define NNZV 4194304
#define BB   16

#define NB    128                  // blocks in hist/scatter passes
#define IPT   128                  // items per thread (NNZV / (NB*256))
#define TILE  64                   // rows/cols per accumulation tile
#define RBINS (MM / TILE)          // 256
#define CBINS (NN / TILE)          // 1024
#define CNT_TOT ((RBINS + CBINS) * NB)   // 163840

// ---------------- zuT[n*16+b] = z[b,n]*u[b,n] ----------------
__global__ void k_zuT(const float* __restrict__ z, const float* __restrict__ u,
                      float* __restrict__ zuT) {
    int n = blockIdx.x * 256 + threadIdx.x;
    float f[BB];
#pragma unroll
    for (int b = 0; b < BB; ++b)
        f[b] = z[(size_t)b * NN + n] * u[(size_t)b * NN + n];
    float4* dst = (float4*)(zuT + (size_t)n * BB);
#pragma unroll
    for (int i = 0; i < 4; ++i) dst[i] = ((float4*)f)[i];
}

// ---------------- per-block tile histograms (rows + cols) ----------------
__global__ void k_hist(const int* __restrict__ rows, const int* __restrict__ cols,
                       int* __restrict__ cnt) {
    __shared__ int h[RBINS + CBINS];
    for (int i = threadIdx.x; i < RBINS + CBINS; i += 256) h[i] = 0;
    __syncthreads();
    int base = blockIdx.x * (256 * IPT);
    for (int it = 0; it < IPT; ++it) {
        int k = base + it * 256 + threadIdx.x;
        atomicAdd(&h[rows[k] >> 6], 1);
        atomicAdd(&h[RBINS + (cols[k] >> 6)], 1);
    }
    __syncthreads();
    for (int i = threadIdx.x; i < RBINS + CBINS; i += 256)
        cnt[i * NB + blockIdx.x] = h[i];
}

// ---------------- one-block exclusive scan over cnt[CNT_TOT] (in place) ----
__global__ void k_scan(int* __restrict__ cnt) {
    __shared__ int part[1024];
    const int CH = CNT_TOT / 1024;   // 160
    int tid = threadIdx.x;
    int s = 0;
    for (int i = 0; i < CH; ++i) s += cnt[tid * CH + i];
    part[tid] = s;
    __syncthreads();
    for (int off = 1; off < 1024; off <<= 1) {
        int v = (tid >= off) ? part[tid - off] : 0;
        __syncthreads();
        part[tid] += v;
        __syncthreads();
    }
    int run = part[tid] - s;         // exclusive prefix of this thread's chunk
    for (int i = 0; i < CH; ++i) {
        int c = cnt[tid * CH + i];
        cnt[tid * CH + i] = run;
        run += c;
    }
}

// ---------------- scatter items into tile-contiguous buckets ----------------
// item = (val bits, (gidx<<6) | local_sidx)
__global__ void k_scatter(const int* __restrict__ sidx, const int* __restrict__ gidx,
                          const float* __restrict__ vals, const int* __restrict__ scn,
                          int regionBase, int nbins, int sub,
                          uint2* __restrict__ itembuf) {
    __shared__ int nxt[CBINS];
    for (int i = threadIdx.x; i < nbins; i += 256)
        nxt[i] = scn[regionBase + i * NB + blockIdx.x];
    __syncthreads();
    int base = blockIdx.x * (256 * IPT);
    for (int it = 0; it < IPT; ++it) {
        int k = base + it * 256 + threadIdx.x;
        int s = sidx[k];
        unsigned g = (unsigned)gidx[k];
        float v = vals[k];
        int bin = s >> 6;
        int r = atomicAdd(&nxt[bin], 1);
        itembuf[r - sub] = make_uint2(__float_as_uint(v), (g << 6) | (unsigned)(s & 63));
    }
}

// ---------------- accumulate one 64-wide tile in LDS, write once ------------
__global__ void k_accum(const uint2* __restrict__ itembuf, const int* __restrict__ scn,
                        int regionBase, int ntiles, int sub, int regionEnd,
                        const float* __restrict__ xT, float* __restrict__ outT) {
    __shared__ float acc[TILE * 17];
    for (int i = threadIdx.x; i < TILE * 17; i += blockDim.x) acc[i] = 0.f;
    __syncthreads();
    int t = blockIdx.x;
    int start = scn[regionBase + t * NB];
    int end = (t + 1 < ntiles) ? scn[regionBase + (t + 1) * NB] : regionEnd;
    for (int i = start + (int)threadIdx.x; i < end; i += (int)blockDim.x) {
        uint2 e = itembuf[i - sub];
        float v = __uint_as_float(e.x);
        int g = (int)(e.y >> 6);
        int l = (int)(e.y & 63u);
        const float4* src = (const float4*)(xT + (size_t)g * BB);
        float4 x0 = src[0], x1 = src[1], x2 = src[2], x3 = src[3];
        float* a = acc + l * 17;
        atomicAdd(a + 0,  v * x0.x); atomicAdd(a + 1,  v * x0.y);
        atomicAdd(a + 2,  v * x0.z); atomicAdd(a + 3,  v * x0.w);
        atomicAdd(a + 4,  v * x1.x); atomicAdd(a + 5,  v * x1.y);
        atomicAdd(a + 6,  v * x1.z); atomicAdd(a + 7,  v * x1.w);
        atomicAdd(a + 8,  v * x2.x); atomicAdd(a + 9,  v * x2.y);
        atomicAdd(a + 10, v * x2.z); atomicAdd(a + 11, v * x2.w);
        atomicAdd(a + 12, v * x3.x); atomicAdd(a + 13, v * x3.y);
        atomicAdd(a + 14, v * x3.z); atomicAdd(a + 15, v * x3.w);
    }
    __syncthreads();
    for (int i = threadIdx.x; i < TILE * BB; i += blockDim.x) {
        int l = i >> 4, b = i & 15;
        outT[((size_t)t * TILE + l) * BB + b] = acc[l * 17 + b];
    }
}

// ---------------- rT[m*16+b] = y[b,m] - t1T[m*16+b] ----------------
__global__ void k_rT(const float* __restrict__ y, const float* __restrict__ t1T,
                     float* __restrict__ rT) {
    int m = blockIdx.x * 256 + threadIdx.x;
    float t[BB];
#pragma unroll
    for (int i = 0; i < 4; ++i)
        ((float4*)t)[i] = ((const float4*)(t1T + (size_t)m * BB))[i];
    float f[BB];
#pragma unroll
    for (int b = 0; b < BB; ++b)
        f[b] = y[(size_t)b * MM + m] - t[b];
#pragma unroll
    for (int i = 0; i < 4; ++i)
        ((float4*)(rT + (size_t)m * BB))[i] = ((float4*)f)[i];
}

// ---------------- norm2[b] += sum_n (u[b,n]*t2T[n,b])^2 ----------------
__global__ void k_norm(const float* __restrict__ u, const float* __restrict__ t2T,
                       float* __restrict__ norm2) {
    int n = blockIdx.x * 256 + threadIdx.x;
    float t[BB];
#pragma unroll
    for (int i = 0; i < 4; ++i)
        ((float4*)t)[i] = ((const float4*)(t2T + (size_t)n * BB))[i];
    float acc[BB];
#pragma unroll
    for (int b = 0; b < BB; ++b) {
        float v = u[(size_t)b * NN + n] * t[b];
        acc[b] = v * v;
    }
#pragma unroll
    for (int b = 0; b < BB; ++b) {
#pragma unroll
        for (int off = 32; off; off >>= 1)
            acc[b] += __shfl_xor(acc[b], off, 64);
    }
    int lane = threadIdx.x & 63;
#pragma unroll
    for (int b = 0; b < BB; ++b)
        if (lane == b) unsafeAtomicAdd(norm2 + b, acc[b]);
}

// ---------------- out[b,n] = z[b,n] - eta * v / max(1,||v||) ----------------
__global__ void k_final(const float* __restrict__ z, const float* __restrict__ u,
                        const float* __restrict__ t2T, const float* __restrict__ norm2,
                        const float* __restrict__ eta, float* __restrict__ out) {
    int n = blockIdx.x * 256 + threadIdx.x;
    float t[BB];
#pragma unroll
    for (int i = 0; i < 4; ++i)
        ((float4*)t)[i] = ((const float4*)(t2T + (size_t)n * BB))[i];
    float e = eta[0];
#pragma unroll
    for (int b = 0; b < BB; ++b) {
        float denom = fmaxf(1.0f, sqrtf(norm2[b]));
        float v = u[(size_t)b * NN + n] * t[b];
        out[(size_t)b * NN + n] = z[(size_t)b * NN + n] - e * v / denom;
    }
}

extern "C" void kernel_launch(void* const* d_in, const int* in_sizes, int n_in,
                              void* d_out, int out_size, void* d_ws, size_t ws_size,
                              hipStream_t stream) {
    const float* z      = (const float*)d_in[0];
    const float* u      = (const float*)d_in[1];
    const float* y      = (const float*)d_in[2];
    const float* A_vals = (const float*)d_in[3];
    const int*   A_rows = (const int*)d_in[4];
    const int*   A_cols = (const int*)d_in[5];
    const float* eta    = (const float*)d_in[6];
    float* out = (float*)d_out;

    char* ws = (char*)d_ws;
    float* zuT    = (float*)(ws);                        // 4 MB  [N][B]
    float* t2T    = (float*)(ws + (4u  << 20));          // 4 MB  [N][B]
    float* t1T    = (float*)(ws + (8u  << 20));          // 1 MB  [M][B]
    float* rT     = (float*)(ws + (9u  << 20));          // 1 MB  [M][B]
    float* norm2  = (float*)(ws + (10u << 20));          // 64 B
    int*   scn    = (int*)  (ws + (10u << 20) + 4096);   // 640 KB counts/bases
    uint2* items  = (uint2*)(ws + (11u << 20));          // 33.5 MB bucket buffer

    hipMemsetAsync(norm2, 0, BB * sizeof(float), stream);

    k_zuT<<<NN / 256, 256, 0, stream>>>(z, u, zuT);
    k_hist<<<NB, 256, 0, stream>>>(A_rows, A_cols, scn);
    k_scan<<<1, 1024, 0, stream>>>(scn);

    // ---- t1 = A(zu): bucket by row tile, gather zuT[col] ----
    k_scatter<<<NB, 256, 0, stream>>>(A_rows, A_cols, A_vals, scn,
                                      /*regionBase=*/0, RBINS, /*sub=*/0, items);
    k_accum<<<RBINS, 512, 0, stream>>>(items, scn, /*regionBase=*/0, RBINS,
                                       /*sub=*/0, /*regionEnd=*/NNZV, zuT, t1T);
    k_rT<<<MM / 256, 256, 0, stream>>>(y, t1T, rT);

    // ---- t2 = A^T(r): bucket by col tile, gather rT[row] ----
    k_scatter<<<NB, 256, 0, stream>>>(A_cols, A_rows, A_vals, scn,
                                      /*regionBase=*/RBINS * NB, CBINS, /*sub=*/NNZV, items);
    k_accum<<<CBINS, 512, 0, stream>>>(items, scn, /*regionBase=*/RBINS * NB, CBINS,
                                       /*sub=*/NNZV, /*regionEnd=*/2 * NNZV, rT, t2T);

    k_norm<<<NN / 256, 256, 0, stream>>>(u, t2T, norm2);
    k_final<<<NN / 256, 256, 0, stream>>>(z, u, t2T, norm2, eta, out);
}